// Round 2
// baseline (538.544 us; speedup 1.0000x reference)
//
#include <hip/hip_runtime.h>

#define EPSV 1e-5f

typedef short bf16x8 __attribute__((ext_vector_type(8)));
typedef float f32x4 __attribute__((ext_vector_type(4)));

__device__ __forceinline__ float sigmoidf_(float x) {
  return 1.f / (1.f + __expf(-x));
}
__device__ __forceinline__ unsigned short f2bf(float f) {
  unsigned int u = __float_as_uint(f);
  u += 0x7fffu + ((u >> 16) & 1u);
  return (unsigned short)(u >> 16);
}
__device__ __forceinline__ float bfu(unsigned short h) {
  union { unsigned int u; float f; } t; t.u = ((unsigned int)h) << 16; return t.f;
}
__device__ __forceinline__ float bflo(unsigned int u) {
  union { unsigned int x; float f; } t; t.x = u << 16; return t.f;
}
__device__ __forceinline__ float bfhi(unsigned int u) {
  union { unsigned int x; float f; } t; t.x = u & 0xffff0000u; return t.f;
}

// ---------------------------------------------------------------------------
// W_comb[i][m][k] = sum_j fusion_W[p][m][d*64+j] * out_W[i][j][k]
// ---------------------------------------------------------------------------
__global__ __launch_bounds__(256) void precomp_wc(
    const float* __restrict__ fW,   // (2,64,128)
    const float* __restrict__ oW,   // (4,64,128)
    float* __restrict__ Wc)         // (4,64,128)
{
  const int bi = blockIdx.x;
  const int i = bi >> 3, mg = bi & 7;
  const int m = (mg << 3) + (threadIdx.x >> 5);
  const int k0 = (threadIdx.x & 31) << 2;
  const int p = i >> 1, d = i & 1;
  const float* fr = fW + p * 8192 + m * 128 + d * 64;
  const float* orow = oW + i * 8192 + k0;
  float a0 = 0.f, a1 = 0.f, a2 = 0.f, a3 = 0.f;
  for (int j = 0; j < 64; ++j) {
    const float f = fr[j];
    const float4 o4 = *(const float4*)(orow + j * 128);
    a0 += f * o4.x; a1 += f * o4.y; a2 += f * o4.z; a3 += f * o4.w;
  }
  float* out = Wc + i * 8192 + m * 128 + k0;
  out[0] = a0; out[1] = a1; out[2] = a2; out[3] = a3;
}

// ---------------------------------------------------------------------------
// Wc -> bf16 MFMA B-fragment order: WcF[ip][tile(4)][h(4)][lane(64)][8]
// ---------------------------------------------------------------------------
__global__ __launch_bounds__(256) void precomp_wcf(
    const float* __restrict__ Wc, unsigned short* __restrict__ WcF)
{
  const int ip = blockIdx.x;
  const float* src = Wc + (size_t)ip * 8192;
  unsigned short* dst = WcF + (size_t)ip * 8192;
  for (int idx = threadIdx.x; idx < 8192; idx += 256) {
    const int tile = idx >> 11;
    const int h = (idx >> 9) & 3;
    const int lane = (idx >> 3) & 63;
    const int j = idx & 7;
    const int col = lane & 15, quad = lane >> 4;
    dst[idx] = f2bf(src[(tile * 16 + col) * 128 + h * 32 + quad * 8 + j]);
  }
}

// ---------------------------------------------------------------------------
// in_proj weights -> bf16 in MFMA B-fragment order (1KB coalesced per wave).
// ---------------------------------------------------------------------------
__global__ __launch_bounds__(256) void precomp_wpf(
    const float* __restrict__ Wp, unsigned short* __restrict__ WpF)
{
  const int ip = blockIdx.x;
  const float* src = Wp + (size_t)ip * 24704;
  unsigned short* dst = WpF + (size_t)ip * 25600;
  for (int idx = threadIdx.x; idx < 25600; idx += 256) {
    const int tile = idx >> 10;
    const int rem = idx & 1023;
    const int h = rem >> 9;
    const int lane = (rem >> 3) & 63;
    const int j = idx & 7;
    const int col = lane & 15, quad = lane >> 4;
    const int o = tile * 16 + col;
    const int k = h * 32 + quad * 8 + j;
    dst[idx] = (o < 386) ? f2bf(src[o * 64 + k]) : (unsigned short)0;
  }
}

// ---------------------------------------------------------------------------
// transp0: x0[b][t][f][c] = x[b][c][t][f]
// ---------------------------------------------------------------------------
__global__ __launch_bounds__(256) void transp0(
    const float* __restrict__ x, float* __restrict__ x0)
{
  __shared__ float T[64 * 132];
  const int tid = threadIdx.x, blk = blockIdx.x;
  const int b = blk >> 7, t = blk & 127;
  {
    const int c = tid >> 2, f0 = (tid & 3) << 5;
    const float* xp = x + (((size_t)(b * 64 + c) * 128 + t) << 7) + f0;
    float* tp = &T[c * 132 + f0];
    #pragma unroll
    for (int j = 0; j < 8; ++j)
      *(float4*)(tp + (j << 2)) = *(const float4*)(xp + (j << 2));
  }
  __syncthreads();
  {
    const int f = tid >> 1, cb = (tid & 1) << 5;
    float* op = x0 + (((size_t)(b * 128 + t) * 128 + f) << 6) + cb;
    #pragma unroll
    for (int j = 0; j < 32; j += 4) {
      float4 v;
      v.x = T[(cb + j + 0) * 132 + f];
      v.y = T[(cb + j + 1) * 132 + f];
      v.z = T[(cb + j + 2) * 132 + f];
      v.w = T[(cb + j + 3) * 132 + f];
      *(float4*)(op + j) = v;
    }
  }
}

// ---------------------------------------------------------------------------
// One block = one (sequence, direction). Chunked-SSD with 32-step chunks:
// per chunk the scan is full-K MFMAs
//   G = C B^T (3 tiles, 3 waves) ; y_inter = P_t (C h^T) (4 waves)
//   h' = At h + X^T (w.B) (4 waves) ; y_intra = (M.G) X (4 waves)
// h kept in f32 MFMA accumulators across chunks; bf16 snapshot only feeds
// y_inter. 8 barriers/chunk x 4 chunks. LDS ~79.6 KB -> 2 blocks/CU.
// ---------------------------------------------------------------------------
__global__ __launch_bounds__(512, 4) void mamba_dir(
    const float* __restrict__ src,   // [seq][pos][c] f32 (x0 or x1)
    unsigned short* __restrict__ ybuf, // bf16 [dir][seq][pos][64]
    const unsigned short* __restrict__ WpF, // bf16 fragments (4,25600)
    const unsigned short* __restrict__ WcF, // bf16 fragments (4,8192)
    const float* __restrict__ cwA, const float* __restrict__ cbA,
    const float* __restrict__ dtbA, const float* __restrict__ AlA,
    const float* __restrict__ DpA, const float* __restrict__ nwA,
    const float* __restrict__ lnwA, const float* __restrict__ lnbA,
    int phase)
{
  // overlays (disjoint live ranges):
  //  u0 : sU (P1-P2) | sSm (P5-P6)
  //  uXY: raw xBC bf16 [32][264] (P2-P4) | y f32 [32][132] (P6-P7)
  __shared__ __align__(16) unsigned char u0[5120];
  __shared__ __align__(16) unsigned char uXY[16896];
  __shared__ __align__(16) unsigned short sZb[32 * 136];   // z then g
  __shared__ __align__(16) unsigned short sBC16[32 * 136]; // B(0-63) C(64-127)
  __shared__ __align__(16) unsigned short sXdT[128 * 40];  // x^T [c][t]
  __shared__ __align__(16) unsigned short sBTw[2 * 64 * 40]; // (w.B)^T [h][n][t]
  __shared__ __align__(16) unsigned short sH[2 * 64 * 72]; // h snapshot [h][p][n]
  __shared__ float sMeta[32][2][4];   // per (t,h): {L, dt, w, P}
  __shared__ float sDtRaw[32][2];

  unsigned short* sU   = (unsigned short*)u0;   // [32][72]
  unsigned short* sSm  = (unsigned short*)u0;   // [2][32][40]
  unsigned short* sRaw = (unsigned short*)uXY;  // [32][264]
  float*          sY   = (float*)uXY;           // [32][132]

  const int tid = threadIdx.x;
  const int blk = blockIdx.x;
  const int seq = blk >> 1, dir = blk & 1;
  const int ip = (phase << 1) + dir;
  const float dtb0 = dtbA[ip * 2], dtb1 = dtbA[ip * 2 + 1];
  const float nA0 = -__expf(AlA[ip * 2]), nA1 = -__expf(AlA[ip * 2 + 1]);
  const float Dp0 = DpA[ip * 2], Dp1 = DpA[ip * 2 + 1];

  const int wv = tid >> 6, lane = tid & 63;
  const int col = lane & 15, quad = lane >> 4;

  // conv role: w0,1 = x lh0; w4,5 = x lh1; w2,3 = B (P4); w6,7 = C (P3)
  int convC, convLH;
  if (tid < 128)      { convC = tid;              convLH = 0; }
  else if (tid < 256) { convC = 128 + (tid & 63); convLH = (tid >> 6) & 1; }
  else if (tid < 384) { convC = tid - 256;        convLH = 1; }
  else                { convC = 192 + (tid & 63); convLH = (tid >> 6) & 1; }
  const int lt0 = convLH << 4;
  const float4 cw4 = *(const float4*)(cwA + ip * 1024 + (convC << 2));
  const float cbias = cbA[ip * 256 + convC];
  float ch0 = 0.f, ch1 = 0.f, ch2 = 0.f;   // conv carry (lh==0 threads)

  f32x4 hacc[8];  // waves 0-3: h state, [pt*4+nt]
  #pragma unroll
  for (int i = 0; i < 8; ++i) hacc[i] = (f32x4){0.f, 0.f, 0.f, 0.f};

  const unsigned short* wf = WpF + (size_t)ip * 25600;
  const unsigned short* wcf = WcF + (size_t)ip * 8192;
  const size_t sb = (size_t)seq << 13;
  const int lnb_i = (phase << 6) + lane;
  const float lnw_v = lnwA[lnb_i], lnb_v = lnbA[lnb_i];

  // preload chunk 0 (4 floats/thread, coalesced)
  float vc[4], vn[4];
  #pragma unroll
  for (int h = 0; h < 4; ++h) {
    const int st = wv + (h << 3);
    const int p = dir ? (127 - st) : st;
    vc[h] = src[sb + (size_t)p * 64 + lane];
  }

  for (int ck = 0; ck < 4; ++ck) {
    // ---- prefetch next chunk ----
    #pragma unroll
    for (int h = 0; h < 4; ++h) vn[h] = 0.f;
    if (ck < 3) {
      #pragma unroll
      for (int h = 0; h < 4; ++h) {
        const int st = ((ck + 1) << 5) + wv + (h << 3);
        const int p = dir ? (127 - st) : st;
        vn[h] = src[sb + (size_t)p * 64 + lane];
      }
    }
    // ---- P1: layernorm in registers (wave-shfl), write bf16 sU ----
    #pragma unroll
    for (int h = 0; h < 4; ++h) {
      const float v = vc[h];
      float sm = v, s2 = v * v;
      sm += __shfl_xor(sm, 1);  s2 += __shfl_xor(s2, 1);
      sm += __shfl_xor(sm, 2);  s2 += __shfl_xor(s2, 2);
      sm += __shfl_xor(sm, 4);  s2 += __shfl_xor(s2, 4);
      sm += __shfl_xor(sm, 8);  s2 += __shfl_xor(s2, 8);
      sm += __shfl_xor(sm, 16); s2 += __shfl_xor(s2, 16);
      sm += __shfl_xor(sm, 32); s2 += __shfl_xor(s2, 32);
      const float mean = sm * (1.f / 64.f);
      const float inv = rsqrtf(s2 * (1.f / 64.f) - mean * mean + EPSV);
      sU[(wv + (h << 3)) * 72 + lane] = f2bf((v - mean) * inv * lnw_v + lnb_v);
    }
    __syncthreads();   // B1
    // ---- P2: in_proj via MFMA, 50 jobs (tile, row-half) over 8 waves ----
    {
      const int rt = wv & 1;
      const bf16x8 a0 = *(const bf16x8*)(&sU[(rt * 16 + col) * 72 + quad * 8]);
      const bf16x8 a1 = *(const bf16x8*)(&sU[(rt * 16 + col) * 72 + 32 + quad * 8]);
      for (int j = wv; j < 50; j += 8) {
        const int tile = j >> 1;
        const unsigned short* wt = wf + (tile << 10) + (lane << 3);
        const bf16x8 b0 = *(const bf16x8*)(wt);
        const bf16x8 b1 = *(const bf16x8*)(wt + 512);
        f32x4 d = {0.f, 0.f, 0.f, 0.f};
        d = __builtin_amdgcn_mfma_f32_16x16x32_bf16(a0, b0, d, 0, 0, 0);
        d = __builtin_amdgcn_mfma_f32_16x16x32_bf16(a1, b1, d, 0, 0, 0);
        const int o = (tile << 4) + col;
        const int row = rt * 16 + quad * 4;
        if (tile < 8) {               // z -> bf16
          #pragma unroll
          for (int r = 0; r < 4; ++r)
            sZb[(row + r) * 136 + o] = f2bf(d[r]);
        } else if (tile < 24) {       // raw xBC -> bf16
          #pragma unroll
          for (int r = 0; r < 4; ++r)
            sRaw[(row + r) * 264 + (o - 128)] = f2bf(d[r]);
        } else if (col < 2) {         // dt raw (o = 384,385)
          #pragma unroll
          for (int r = 0; r < 4; ++r)
            sDtRaw[row + r][col] = d[r];
        }
      }
    }
    __syncthreads();   // B2
    // ---- P3: conv x (w0,1,4,5) + conv C (w6,7) + meta (w3) ----
    if (tid < 128 || (tid >= 256 && tid < 384)) {
      const int c = convC;
      float a0c, a1c, a2c;
      if (convLH == 0) { a0c = ch0; a1c = ch1; a2c = ch2; }
      else {
        a0c = bfu(sRaw[13 * 264 + c]);
        a1c = bfu(sRaw[14 * 264 + c]);
        a2c = bfu(sRaw[15 * 264 + c]);
      }
      unsigned int pk[8];
      #pragma unroll
      for (int l = 0; l < 16; ++l) {
        const float a3 = bfu(sRaw[(lt0 + l) * 264 + c]);
        const float acc = cbias + a0c * cw4.x + a1c * cw4.y + a2c * cw4.z + a3 * cw4.w;
        const unsigned int hv = (unsigned int)f2bf(acc * sigmoidf_(acc));
        if (l & 1) pk[l >> 1] |= hv << 16; else pk[l >> 1] = hv;
        a0c = a1c; a1c = a2c; a2c = a3;
      }
      *(uint4*)(&sXdT[c * 40 + lt0]) = make_uint4(pk[0], pk[1], pk[2], pk[3]);
      *(uint4*)(&sXdT[c * 40 + lt0 + 8]) = make_uint4(pk[4], pk[5], pk[6], pk[7]);
      if (convLH == 0) {
        ch0 = bfu(sRaw[29 * 264 + c]);
        ch1 = bfu(sRaw[30 * 264 + c]);
        ch2 = bfu(sRaw[31 * 264 + c]);
      }
    } else if (tid >= 384) {
      const int c = convC;    // 192..255 -> C col c-192
      float a0c, a1c, a2c;
      if (convLH == 0) { a0c = ch0; a1c = ch1; a2c = ch2; }
      else {
        a0c = bfu(sRaw[13 * 264 + c]);
        a1c = bfu(sRaw[14 * 264 + c]);
        a2c = bfu(sRaw[15 * 264 + c]);
      }
      #pragma unroll
      for (int l = 0; l < 16; ++l) {
        const int lt = lt0 + l;
        const float a3 = bfu(sRaw[lt * 264 + c]);
        const float acc = cbias + a0c * cw4.x + a1c * cw4.y + a2c * cw4.z + a3 * cw4.w;
        sBC16[lt * 136 + 64 + (c - 192)] = f2bf(acc * sigmoidf_(acc));
        a0c = a1c; a1c = a2c; a2c = a3;
      }
      if (convLH == 0) {
        ch0 = bfu(sRaw[29 * 264 + c]);
        ch1 = bfu(sRaw[30 * 264 + c]);
        ch2 = bfu(sRaw[31 * 264 + c]);
      }
    } else if (tid >= 192) {   // wave 3: dt / L meta
      const int ml = tid - 192;
      const int t = ml >> 1, hh = ml & 1;
      const float rawv = sDtRaw[t][hh] + (hh ? dtb1 : dtb0);
      const float dtv = (rawv > 20.f) ? rawv : log1pf(__expf(rawv));
      float Lx = dtv * (hh ? nA1 : nA0);   // log dA_t
      #pragma unroll
      for (int d = 2; d < 64; d <<= 1) {   // inclusive prefix over t
        const float tpv = __shfl_up(Lx, d);
        if (ml >= d) Lx += tpv;
      }
      const float Ltot = __shfl(Lx, 62 + hh);
      *(float4*)(&sMeta[t][hh][0]) =
          make_float4(Lx, dtv, __expf(Ltot - Lx) * dtv, __expf(Lx));
    }
    __syncthreads();   // B3
    // ---- P4: conv B + scaled (w.B)^T (w2,3)  ||  y_inter (w4-7) ----
    f32x4 yAcc[4];
    if (tid >= 128 && tid < 256) {
      const int c = convC, n = c - 128;
      float a0c, a1c, a2c;
      if (convLH == 0) { a0c = ch0; a1c = ch1; a2c = ch2; }
      else {
        a0c = bfu(sRaw[13 * 264 + c]);
        a1c = bfu(sRaw[14 * 264 + c]);
        a2c = bfu(sRaw[15 * 264 + c]);
      }
      unsigned int pk0[8], pk1[8];
      #pragma unroll
      for (int l = 0; l < 16; ++l) {
        const int lt = lt0 + l;
        const float a3 = bfu(sRaw[lt * 264 + c]);
        const float acc = cbias + a0c * cw4.x + a1c * cw4.y + a2c * cw4.z + a3 * cw4.w;
        const float bv = acc * sigmoidf_(acc);
        sBC16[lt * 136 + n] = f2bf(bv);
        const unsigned int h0 = (unsigned int)f2bf(bv * sMeta[lt][0][2]);
        const unsigned int h1 = (unsigned int)f2bf(bv * sMeta[lt][1][2]);
        if (l & 1) { pk0[l >> 1] |= h0 << 16; pk1[l >> 1] |= h1 << 16; }
        else       { pk0[l >> 1] = h0;        pk1[l >> 1] = h1; }
        a0c = a1c; a1c = a2c; a2c = a3;
      }
      *(uint4*)(&sBTw[n * 40 + lt0])        = make_uint4(pk0[0], pk0[1], pk0[2], pk0[3]);
      *(uint4*)(&sBTw[n * 40 + lt0 + 8])    = make_uint4(pk0[4], pk0[5], pk0[6], pk0[7]);
      *(uint4*)(&sBTw[2560 + n * 40 + lt0]) = make_uint4(pk1[0], pk1[1], pk1[2], pk1[3]);
      *(uint4*)(&sBTw[2560 + n * 40 + lt0 + 8]) = make_uint4(pk1[4], pk1[5], pk1[6], pk1[7]);
      if (convLH == 0) {
        ch0 = bfu(sRaw[29 * 264 + c]);
        ch1 = bfu(sRaw[30 * 264 + c]);
        ch2 = bfu(sRaw[31 * 264 + c]);
      }
    } else if (wv >= 4) {
      const int q = wv - 4, th = q >> 1, hq = q & 1;
      if (ck) {
        const bf16x8 ca0 = *(const bf16x8*)(&sBC16[(th * 16 + col) * 136 + 64 + quad * 8]);
        const bf16x8 ca1 = *(const bf16x8*)(&sBC16[(th * 16 + col) * 136 + 96 + quad * 8]);
        #pragma unroll
        for (int pt = 0; pt < 4; ++pt) {
          const unsigned short* hp = &sH[(hq * 64 + pt * 16 + col) * 72];
          const bf16x8 h0 = *(const bf16x8*)(hp + quad * 8);
          const bf16x8 h1 = *(const bf16x8*)(hp + 32 + quad * 8);
          f32x4 d = {0.f, 0.f, 0.f, 0.f};
          d = __builtin_amdgcn_mfma_f32_16x16x32_bf16(ca0, h0, d, 0, 0, 0);
          d = __builtin_amdgcn_mfma_f32_16x16x32_bf16(ca1, h1, d, 0, 0, 0);
          yAcc[pt] = d;
        }
        #pragma unroll
        for (int r = 0; r < 4; ++r) {
          const float Pv = sMeta[th * 16 + quad * 4 + r][hq][3];
          yAcc[0][r] *= Pv; yAcc[1][r] *= Pv; yAcc[2][r] *= Pv; yAcc[3][r] *= Pv;
        }
      } else {
        #pragma unroll
        for (int pt = 0; pt < 4; ++pt) yAcc[pt] = (f32x4){0.f, 0.f, 0.f, 0.f};
      }
    }
    __syncthreads();   // B4
    // ---- P5: h-update (w0-3)  ||  G+mask (w4-6)  ||  zero (0,1) (w7) ----
    if (wv < 4) {
      if (ck < 3) {
        const int h = wv >> 1, pbL = (wv & 1) * 32;
        const float At = sMeta[31][h][3];
        const bf16x8 xa0 = *(const bf16x8*)(&sXdT[(h * 64 + pbL + col) * 40 + quad * 8]);
        const bf16x8 xa1 = *(const bf16x8*)(&sXdT[(h * 64 + pbL + 16 + col) * 40 + quad * 8]);
        #pragma unroll
        for (int nt = 0; nt < 4; ++nt) {
          const bf16x8 bb = *(const bf16x8*)(&sBTw[h * 2560 + (nt * 16 + col) * 40 + quad * 8]);
          #pragma unroll
          for (int r = 0; r < 4; ++r) { hacc[nt][r] *= At; hacc[nt + 4][r] *= At; }
          hacc[nt]     = __builtin_amdgcn_mfma_f32_16x16x32_bf16(xa0, bb, hacc[nt], 0, 0, 0);
          hacc[nt + 4] = __builtin_amdgcn_mfma_f32_16x16x32_bf16(xa1, bb, hacc[nt + 4], 0, 0, 0);
        }
      }
    } else if (wv < 7) {
      const int q = wv - 4;
      const int th = (q > 0) ? 1 : 0, sh = (q == 2) ? 1 : 0;
      const bf16x8 ca0 = *(const bf16x8*)(&sBC16[(th * 16 + col) * 136 + 64 + quad * 8]);
      const bf16x8 ca1 = *(const bf16x8*)(&sBC16[(th * 16 + col) * 136 + 96 + quad * 8]);
      const bf16x8 bb0 = *(const bf16x8*)(&sBC16[(sh * 16 + col) * 136 + quad * 8]);
      const bf16x8 bb1 = *(const bf16x8*)(&sBC16[(sh * 16 + col) * 136 + 32 + quad * 8]);
      f32x4 g = {0.f, 0.f, 0.f, 0.f};
      g = __builtin_amdgcn_mfma_f32_16x16x32_bf16(ca0, bb0, g, 0, 0, 0);
      g = __builtin_amdgcn_mfma_f32_16x16x32_bf16(ca1, bb1, g, 0, 0, 0);
      const int s = sh * 16 + col;
      #pragma unroll
      for (int h = 0; h < 2; ++h) {
        const float Ls = sMeta[s][h][0], dts = sMeta[s][h][1];
        #pragma unroll
        for (int r = 0; r < 4; ++r) {
          const int t = th * 16 + quad * 4 + r;
          const float m = (s <= t) ? __expf(sMeta[t][h][0] - Ls) * dts : 0.f;
          sSm[h * 1280 + t * 40 + s] = f2bf(g[r] * m);
        }
      }
    } else {
      // zero score tile (t<16, s>=16) for both heads (sU clobbered it in P1)
      const int hz = lane >> 5, tz = (lane >> 1) & 15, pz = lane & 1;
      *(uint4*)(&sSm[hz * 1280 + tz * 40 + 16 + pz * 8]) = make_uint4(0u, 0u, 0u, 0u);
    }
    __syncthreads();   // B5
    // ---- P6: y_intra + D*x + y write (w4-7)  ||  h snapshot (w0-3) ----
    if (wv >= 4) {
      const int q = wv - 4, th = q >> 1, hq = q & 1;
      const float dp = hq ? Dp1 : Dp0;
      const bf16x8 sa = *(const bf16x8*)(&sSm[hq * 1280 + (th * 16 + col) * 40 + quad * 8]);
      #pragma unroll
      for (int ct = 0; ct < 4; ++ct) {
        const int c = hq * 64 + ct * 16 + col;
        const bf16x8 xb = *(const bf16x8*)(&sXdT[c * 40 + quad * 8]);
        yAcc[ct] = __builtin_amdgcn_mfma_f32_16x16x32_bf16(sa, xb, yAcc[ct], 0, 0, 0);
        const uint2 xw = *(const uint2*)(&sXdT[c * 40 + th * 16 + quad * 4]);
        yAcc[ct][0] += dp * bflo(xw.x);
        yAcc[ct][1] += dp * bfhi(xw.x);
        yAcc[ct][2] += dp * bflo(xw.y);
        yAcc[ct][3] += dp * bfhi(xw.y);
        #pragma unroll
        for (int r = 0; r < 4; ++r)
          sY[(th * 16 + quad * 4 + r) * 132 + c] = yAcc[ct][r];
      }
    } else if (ck < 3) {
      const int h = wv >> 1, pbL = (wv & 1) * 32;
      #pragma unroll
      for (int nt = 0; nt < 4; ++nt) {
        #pragma unroll
        for (int r = 0; r < 4; ++r) {
          sH[(h * 64 + pbL + quad * 4 + r) * 72 + nt * 16 + col] = f2bf(hacc[nt][r]);
          sH[(h * 64 + pbL + 16 + quad * 4 + r) * 72 + nt * 16 + col] = f2bf(hacc[nt + 4][r]);
        }
      }
    }
    __syncthreads();   // B6
    // ---- P7: gate with silu(z) + rmsnorm -> bf16 g IN PLACE over z ----
    {
      const int k0 = lane << 1;
      #pragma unroll
      for (int sub = 0; sub < 4; ++sub) {
        const int lt = wv + (sub << 3);
        const float2 yv = *(const float2*)(&sY[lt * 132 + k0]);
        const unsigned int zp = *(const unsigned int*)(&sZb[lt * 136 + k0]);
        const float z0 = bflo(zp), z1 = bfhi(zp);
        const float g0 = yv.x * (z0 * sigmoidf_(z0));
        const float g1 = yv.y * (z1 * sigmoidf_(z1));
        float ssq = g0 * g0 + g1 * g1;
        ssq += __shfl_xor(ssq, 1);
        ssq += __shfl_xor(ssq, 2);
        ssq += __shfl_xor(ssq, 4);
        ssq += __shfl_xor(ssq, 8);
        ssq += __shfl_xor(ssq, 16);
        ssq += __shfl_xor(ssq, 32);
        const float sc = rsqrtf(ssq * (1.f / 128.f) + EPSV);
        const float2 nw2 = *(const float2*)(nwA + ip * 128 + k0);
        const unsigned int lo = f2bf(g0 * sc * nw2.x);
        const unsigned int hi = f2bf(g1 * sc * nw2.y);
        *(unsigned int*)(&sZb[lt * 136 + k0]) = lo | (hi << 16);
      }
    }
    __syncthreads();   // B7
    // ---- P8: out-matmul, 8 jobs (row-half, m-tile) over 8 waves ----
    {
      const int rt = wv >> 2, mt = wv & 3;
      const unsigned short* wt = wcf + (mt << 11);
      f32x4 d = {0.f, 0.f, 0.f, 0.f};
      #pragma unroll
      for (int h = 0; h < 4; ++h) {
        const bf16x8 a = *(const bf16x8*)(&sZb[(rt * 16 + col) * 136 + (h << 5) + (quad << 3)]);
        const bf16x8 bb = *(const bf16x8*)(wt + (h << 9) + (lane << 3));
        d = __builtin_amdgcn_mfma_f32_16x16x32_bf16(a, bb, d, 0, 0, 0);
      }
      const size_t yb = ((size_t)(dir * 512 + seq) * 128) << 6;
      #pragma unroll
      for (int r = 0; r < 4; ++r) {
        const int st = (ck << 5) + rt * 16 + (quad << 2) + r;
        const int rp = dir ? (127 - st) : st;
        ybuf[yb + ((size_t)rp << 6) + (mt << 4) + col] = f2bf(d[r]);
      }
    }
    __syncthreads();   // B8
    #pragma unroll
    for (int h = 0; h < 4; ++h) vc[h] = vn[h];
  }
}

// ---------------------------------------------------------------------------
// combine0: x1[b][f][t][c] = x[b][c][t][f] + yf + yb + fb0[c]   (coalesced)
// ---------------------------------------------------------------------------
__global__ __launch_bounds__(256) void combine0(
    const float* __restrict__ x, const unsigned short* __restrict__ ybuf,
    const float* __restrict__ fb, float* __restrict__ x1)
{
  __shared__ float T[64 * 132];
  const int tid = threadIdx.x, blk = blockIdx.x;
  const int b = blk >> 7, t = blk & 127;
  {
    const int c = tid >> 2, f0 = (tid & 3) << 5;
    const float* xp = x + (((size_t)(b * 64 + c) * 128 + t) << 7) + f0;
    float* tp = &T[c * 132 + f0];
    #pragma unroll
    for (int j = 0; j < 8; ++j)
      *(float4*)(tp + (j << 2)) = *(const float4*)(xp + (j << 2));
  }
  __syncthreads();
  {
    const int f = tid >> 1, cb = (tid & 1) << 5;
    const size_t s0 = (size_t)b * 128 + t;
    const unsigned short* yf = ybuf + ((s0 * 128 + f) << 6) + cb;
    const unsigned short* yb = ybuf + (((s0 + 512) * 128 + f) << 6) + cb;
    float* op = x1 + (((size_t)(b * 128 + f) * 128 + t) << 6) + cb;
    #pragma unroll
    for (int j = 0; j < 32; j += 4) {
      float4 v;
      v.x = T[(cb + j + 0) * 132 + f] + bfu(yf[j + 0]) + bfu(yb[j + 0]) + fb[cb + j + 0];
      v.y = T[(cb + j + 1) * 132 + f] + bfu(yf[j + 1]) + bfu(yb[j + 1]) + fb[cb + j + 1];
      v.z = T[(cb + j + 2) * 132 + f] + bfu(yf[j + 2]) + bfu(yb[j + 2]) + fb[cb + j + 2];
      v.w = T[(cb + j + 3) * 132 + f] + bfu(yf[j + 3]) + bfu(yb[j + 3]) + fb[cb + j + 3];
      *(float4*)(op + j) = v;
    }
  }
}

// ---------------------------------------------------------------------------
// combine1: out[b][c][t][f] = x1[b][f][t][c] + yf + yb + fb1[c]  (coalesced)
// ---------------------------------------------------------------------------
__global__ __launch_bounds__(256) void combine1(
    const float* __restrict__ x1, const unsigned short* __restrict__ ybuf,
    const float* __restrict__ fb, float* __restrict__ out)
{
  __shared__ float T[128 * 68];
  const int tid = threadIdx.x, blk = blockIdx.x;
  const int b = blk >> 7, t = blk & 127;
  {
    const int f = tid >> 1, cb = (tid & 1) << 5;
    const size_t s1 = (size_t)b * 128 + f;
    const float* xp = x1 + ((s1 * 128 + t) << 6) + cb;
    const unsigned short* yf = ybuf + ((s1 * 128 + t) << 6) + cb;
    const unsigned short* yb = ybuf + (((s1 + 512) * 128 + t) << 6) + cb;
    float* tp = &T[f * 68 + cb];
    #pragma unroll
    for (int j = 0; j < 32; j += 4) {
      const float4 xv = *(const float4*)(xp + j);
      const uint2 yfv = *(const uint2*)(yf + j);
      const uint2 ybv = *(const uint2*)(yb + j);
      const float4 fv = *(const float4*)(fb + cb + j);
      tp[j + 0] = xv.x + bflo(yfv.x) + bflo(ybv.x) + fv.x;
      tp[j + 1] = xv.y + bfhi(yfv.x) + bfhi(ybv.x) + fv.y;
      tp[j + 2] = xv.z + bflo(yfv.y) + bflo(ybv.y) + fv.z;
      tp[j + 3] = xv.w + bfhi(yfv.y) + bfhi(ybv.y) + fv.w;
    }
  }
  __syncthreads();
  {
    const int c = tid >> 2, f0 = (tid & 3) << 5;
    float* op = out + (((size_t)(b * 64 + c) * 128 + t) << 7) + f0;
    #pragma unroll
    for (int j = 0; j < 32; j += 4) {
      float4 v;
      v.x = T[(f0 + j + 0) * 68 + c];
      v.y = T[(f0 + j + 1) * 68 + c];
      v.z = T[(f0 + j + 2) * 68 + c];
      v.w = T[(f0 + j + 3) * 68 + c];
      *(float4*)(op + j) = v;
    }
  }
}

extern "C" void kernel_launch(void* const* d_in, const int* in_sizes, int n_in,
                              void* d_out, int out_size, void* d_ws, size_t ws_size,
                              hipStream_t stream) {
  const float* x   = (const float*)d_in[0];
  const float* Wp  = (const float*)d_in[1];
  const float* cw  = (const float*)d_in[2];
  const float* cb  = (const float*)d_in[3];
  const float* dtb = (const float*)d_in[4];
  const float* Al  = (const float*)d_in[5];
  const float* Dp  = (const float*)d_in[6];
  const float* nw  = (const float*)d_in[7];
  const float* oW  = (const float*)d_in[8];
  const float* fW  = (const float*)d_in[9];
  const float* fb  = (const float*)d_in[10];
  const float* lnw = (const float*)d_in[11];
  const float* lnb = (const float*)d_in[12];

  float* ws = (float*)d_ws;
  float* Wc = ws;                                       // 32768 f32
  unsigned short* WpF = (unsigned short*)(ws + 32768);  // 102400 shorts
  unsigned short* WcF = (unsigned short*)(ws + 32768 + 51200); // 32768 shorts
  float* xbuf = ws + 32768 + 51200 + 16384;             // 4194304 f32
  unsigned short* y = (unsigned short*)(xbuf + 4194304); // 8388608 bf16

  precomp_wc<<<32, 256, 0, stream>>>(fW, oW, Wc);
  precomp_wcf<<<4, 256, 0, stream>>>(Wc, WcF);
  precomp_wpf<<<4, 256, 0, stream>>>(Wp, WpF);
  transp0<<<512, 256, 0, stream>>>(x, xbuf);
  mamba_dir<<<1024, 512, 0, stream>>>(xbuf, y, WpF, WcF, cw, cb, dtb, Al, Dp,
                                      nw, lnw, lnb, 0);
  combine0<<<512, 256, 0, stream>>>(x, y, fb, xbuf);
  mamba_dir<<<1024, 512, 0, stream>>>(xbuf, y, WpF, WcF, cw, cb, dtb, Al, Dp,
                                      nw, lnw, lnb, 1);
  combine1<<<512, 256, 0, stream>>>(xbuf, y, fb + 64, (float*)d_out);
}

// Round 3
// 437.725 us; speedup vs baseline: 1.2303x; 1.2303x over previous
//
#include <hip/hip_runtime.h>

#define EPSV 1e-5f

typedef short bf16x8 __attribute__((ext_vector_type(8)));
typedef float f32x4 __attribute__((ext_vector_type(4)));

__device__ __forceinline__ float sigmoidf_(float x) {
  return 1.f / (1.f + __expf(-x));
}
__device__ __forceinline__ unsigned short f2bf(float f) {
  unsigned int u = __float_as_uint(f);
  u += 0x7fffu + ((u >> 16) & 1u);
  return (unsigned short)(u >> 16);
}
__device__ __forceinline__ float bfu(unsigned short h) {
  union { unsigned int u; float f; } t; t.u = ((unsigned int)h) << 16; return t.f;
}
__device__ __forceinline__ float bflo(unsigned int u) {
  union { unsigned int x; float f; } t; t.x = u << 16; return t.f;
}
__device__ __forceinline__ float bfhi(unsigned int u) {
  union { unsigned int x; float f; } t; t.x = u & 0xffff0000u; return t.f;
}

// ---------------------------------------------------------------------------
// W_comb[i][m][k] = sum_j fusion_W[p][m][d*64+j] * out_W[i][j][k]
// ---------------------------------------------------------------------------
__global__ __launch_bounds__(256) void precomp_wc(
    const float* __restrict__ fW,   // (2,64,128)
    const float* __restrict__ oW,   // (4,64,128)
    float* __restrict__ Wc)         // (4,64,128)
{
  const int bi = blockIdx.x;
  const int i = bi >> 3, mg = bi & 7;
  const int m = (mg << 3) + (threadIdx.x >> 5);
  const int k0 = (threadIdx.x & 31) << 2;
  const int p = i >> 1, d = i & 1;
  const float* fr = fW + p * 8192 + m * 128 + d * 64;
  const float* orow = oW + i * 8192 + k0;
  float a0 = 0.f, a1 = 0.f, a2 = 0.f, a3 = 0.f;
  for (int j = 0; j < 64; ++j) {
    const float f = fr[j];
    const float4 o4 = *(const float4*)(orow + j * 128);
    a0 += f * o4.x; a1 += f * o4.y; a2 += f * o4.z; a3 += f * o4.w;
  }
  float* out = Wc + i * 8192 + m * 128 + k0;
  out[0] = a0; out[1] = a1; out[2] = a2; out[3] = a3;
}

// ---------------------------------------------------------------------------
// Wc -> bf16 MFMA B-fragment order: WcF[ip][tile(4)][h(4)][lane(64)][8]
// ---------------------------------------------------------------------------
__global__ __launch_bounds__(256) void precomp_wcf(
    const float* __restrict__ Wc, unsigned short* __restrict__ WcF)
{
  const int ip = blockIdx.x;
  const float* src = Wc + (size_t)ip * 8192;
  unsigned short* dst = WcF + (size_t)ip * 8192;
  for (int idx = threadIdx.x; idx < 8192; idx += 256) {
    const int tile = idx >> 11;
    const int h = (idx >> 9) & 3;
    const int lane = (idx >> 3) & 63;
    const int j = idx & 7;
    const int col = lane & 15, quad = lane >> 4;
    dst[idx] = f2bf(src[(tile * 16 + col) * 128 + h * 32 + quad * 8 + j]);
  }
}

// ---------------------------------------------------------------------------
// in_proj weights -> bf16 in MFMA B-fragment order (1KB coalesced per wave).
// ---------------------------------------------------------------------------
__global__ __launch_bounds__(256) void precomp_wpf(
    const float* __restrict__ Wp, unsigned short* __restrict__ WpF)
{
  const int ip = blockIdx.x;
  const float* src = Wp + (size_t)ip * 24704;
  unsigned short* dst = WpF + (size_t)ip * 25600;
  for (int idx = threadIdx.x; idx < 25600; idx += 256) {
    const int tile = idx >> 10;
    const int rem = idx & 1023;
    const int h = rem >> 9;
    const int lane = (rem >> 3) & 63;
    const int j = idx & 7;
    const int col = lane & 15, quad = lane >> 4;
    const int o = tile * 16 + col;
    const int k = h * 32 + quad * 8 + j;
    dst[idx] = (o < 386) ? f2bf(src[o * 64 + k]) : (unsigned short)0;
  }
}

// ---------------------------------------------------------------------------
// transp0: x0[b][t][f][c] = x[b][c][t][f]
// ---------------------------------------------------------------------------
__global__ __launch_bounds__(256) void transp0(
    const float* __restrict__ x, float* __restrict__ x0)
{
  __shared__ float T[64 * 132];
  const int tid = threadIdx.x, blk = blockIdx.x;
  const int b = blk >> 7, t = blk & 127;
  {
    const int c = tid >> 2, f0 = (tid & 3) << 5;
    const float* xp = x + (((size_t)(b * 64 + c) * 128 + t) << 7) + f0;
    float* tp = &T[c * 132 + f0];
    #pragma unroll
    for (int j = 0; j < 8; ++j)
      *(float4*)(tp + (j << 2)) = *(const float4*)(xp + (j << 2));
  }
  __syncthreads();
  {
    const int f = tid >> 1, cb = (tid & 1) << 5;
    float* op = x0 + (((size_t)(b * 128 + t) * 128 + f) << 6) + cb;
    #pragma unroll
    for (int j = 0; j < 32; j += 4) {
      float4 v;
      v.x = T[(cb + j + 0) * 132 + f];
      v.y = T[(cb + j + 1) * 132 + f];
      v.z = T[(cb + j + 2) * 132 + f];
      v.w = T[(cb + j + 3) * 132 + f];
      *(float4*)(op + j) = v;
    }
  }
}

// ---------------------------------------------------------------------------
// One block = one (sequence, direction). Chunked-SSD with 32-step chunks.
// __launch_bounds__(512, 2): hipcc treats arg2 as min BLOCKS/CU (CUDA
// semantics) -> VGPR cap 128 (empirical: (512,4) capped at 64 and spilled
// ~0.5 GB of scratch per dispatch in R2). LDS 79.6 KB caps occupancy at
// 2 blocks/CU = 4 waves/SIMD regardless; 4 waves x 128 regs fills the file.
// ---------------------------------------------------------------------------
__global__ __launch_bounds__(512, 2) void mamba_dir(
    const float* __restrict__ src,   // [seq][pos][c] f32 (x0 or x1)
    unsigned short* __restrict__ ybuf, // bf16 [dir][seq][pos][64]
    const unsigned short* __restrict__ WpF, // bf16 fragments (4,25600)
    const unsigned short* __restrict__ WcF, // bf16 fragments (4,8192)
    const float* __restrict__ cwA, const float* __restrict__ cbA,
    const float* __restrict__ dtbA, const float* __restrict__ AlA,
    const float* __restrict__ DpA, const float* __restrict__ nwA,
    const float* __restrict__ lnwA, const float* __restrict__ lnbA,
    int phase)
{
  // overlays (disjoint live ranges):
  //  u0 : sU (P1-P2) | sSm (P5-P6)
  //  uXY: raw xBC bf16 [32][264] (P2-P4) | y f32 [32][132] (P6-P7)
  __shared__ __align__(16) unsigned char u0[5120];
  __shared__ __align__(16) unsigned char uXY[16896];
  __shared__ __align__(16) unsigned short sZb[32 * 136];   // z then g
  __shared__ __align__(16) unsigned short sBC16[32 * 136]; // B(0-63) C(64-127)
  __shared__ __align__(16) unsigned short sXdT[128 * 40];  // x^T [c][t]
  __shared__ __align__(16) unsigned short sBTw[2 * 64 * 40]; // (w.B)^T [h][n][t]
  __shared__ __align__(16) unsigned short sH[2 * 64 * 72]; // h snapshot [h][p][n]
  __shared__ float sMeta[32][2][4];   // per (t,h): {L, dt, w, P}
  __shared__ float sDtRaw[32][2];

  unsigned short* sU   = (unsigned short*)u0;   // [32][72]
  unsigned short* sSm  = (unsigned short*)u0;   // [2][32][40]
  unsigned short* sRaw = (unsigned short*)uXY;  // [32][264]
  float*          sY   = (float*)uXY;           // [32][132]

  const int tid = threadIdx.x;
  const int blk = blockIdx.x;
  const int seq = blk >> 1, dir = blk & 1;
  const int ip = (phase << 1) + dir;
  const float dtb0 = dtbA[ip * 2], dtb1 = dtbA[ip * 2 + 1];
  const float nA0 = -__expf(AlA[ip * 2]), nA1 = -__expf(AlA[ip * 2 + 1]);
  const float Dp0 = DpA[ip * 2], Dp1 = DpA[ip * 2 + 1];

  const int wv = tid >> 6, lane = tid & 63;
  const int col = lane & 15, quad = lane >> 4;

  // conv role: w0,1 = x lh0; w4,5 = x lh1; w2,3 = B (P4); w6,7 = C (P3)
  int convC, convLH;
  if (tid < 128)      { convC = tid;              convLH = 0; }
  else if (tid < 256) { convC = 128 + (tid & 63); convLH = (tid >> 6) & 1; }
  else if (tid < 384) { convC = tid - 256;        convLH = 1; }
  else                { convC = 192 + (tid & 63); convLH = (tid >> 6) & 1; }
  const int lt0 = convLH << 4;
  const float4 cw4 = *(const float4*)(cwA + ip * 1024 + (convC << 2));
  const float cbias = cbA[ip * 256 + convC];
  float ch0 = 0.f, ch1 = 0.f, ch2 = 0.f;   // conv carry (lh==0 threads)

  f32x4 hacc[8];  // waves 0-3: h state, [pt*4+nt]
  #pragma unroll
  for (int i = 0; i < 8; ++i) hacc[i] = (f32x4){0.f, 0.f, 0.f, 0.f};

  const unsigned short* wf = WpF + (size_t)ip * 25600;
  const unsigned short* wcf = WcF + (size_t)ip * 8192;
  const size_t sb = (size_t)seq << 13;
  const int lnb_i = (phase << 6) + lane;
  const float lnw_v = lnwA[lnb_i], lnb_v = lnbA[lnb_i];

  // preload chunk 0 (4 floats/thread, coalesced)
  float vc[4], vn[4];
  #pragma unroll
  for (int h = 0; h < 4; ++h) {
    const int st = wv + (h << 3);
    const int p = dir ? (127 - st) : st;
    vc[h] = src[sb + (size_t)p * 64 + lane];
  }

  for (int ck = 0; ck < 4; ++ck) {
    // ---- prefetch next chunk ----
    #pragma unroll
    for (int h = 0; h < 4; ++h) vn[h] = 0.f;
    if (ck < 3) {
      #pragma unroll
      for (int h = 0; h < 4; ++h) {
        const int st = ((ck + 1) << 5) + wv + (h << 3);
        const int p = dir ? (127 - st) : st;
        vn[h] = src[sb + (size_t)p * 64 + lane];
      }
    }
    // ---- P1: layernorm in registers (wave-shfl), write bf16 sU ----
    #pragma unroll
    for (int h = 0; h < 4; ++h) {
      const float v = vc[h];
      float sm = v, s2 = v * v;
      sm += __shfl_xor(sm, 1);  s2 += __shfl_xor(s2, 1);
      sm += __shfl_xor(sm, 2);  s2 += __shfl_xor(s2, 2);
      sm += __shfl_xor(sm, 4);  s2 += __shfl_xor(s2, 4);
      sm += __shfl_xor(sm, 8);  s2 += __shfl_xor(s2, 8);
      sm += __shfl_xor(sm, 16); s2 += __shfl_xor(s2, 16);
      sm += __shfl_xor(sm, 32); s2 += __shfl_xor(s2, 32);
      const float mean = sm * (1.f / 64.f);
      const float inv = rsqrtf(s2 * (1.f / 64.f) - mean * mean + EPSV);
      sU[(wv + (h << 3)) * 72 + lane] = f2bf((v - mean) * inv * lnw_v + lnb_v);
    }
    __syncthreads();   // B1
    // ---- P2: in_proj via MFMA, 50 jobs (tile, row-half) over 8 waves ----
    {
      const int rt = wv & 1;
      const bf16x8 a0 = *(const bf16x8*)(&sU[(rt * 16 + col) * 72 + quad * 8]);
      const bf16x8 a1 = *(const bf16x8*)(&sU[(rt * 16 + col) * 72 + 32 + quad * 8]);
      for (int j = wv; j < 50; j += 8) {
        const int tile = j >> 1;
        const unsigned short* wt = wf + (tile << 10) + (lane << 3);
        const bf16x8 b0 = *(const bf16x8*)(wt);
        const bf16x8 b1 = *(const bf16x8*)(wt + 512);
        f32x4 d = {0.f, 0.f, 0.f, 0.f};
        d = __builtin_amdgcn_mfma_f32_16x16x32_bf16(a0, b0, d, 0, 0, 0);
        d = __builtin_amdgcn_mfma_f32_16x16x32_bf16(a1, b1, d, 0, 0, 0);
        const int o = (tile << 4) + col;
        const int row = rt * 16 + quad * 4;
        if (tile < 8) {               // z -> bf16
          #pragma unroll
          for (int r = 0; r < 4; ++r)
            sZb[(row + r) * 136 + o] = f2bf(d[r]);
        } else if (tile < 24) {       // raw xBC -> bf16
          #pragma unroll
          for (int r = 0; r < 4; ++r)
            sRaw[(row + r) * 264 + (o - 128)] = f2bf(d[r]);
        } else if (col < 2) {         // dt raw (o = 384,385)
          #pragma unroll
          for (int r = 0; r < 4; ++r)
            sDtRaw[row + r][col] = d[r];
        }
      }
    }
    __syncthreads();   // B2
    // ---- P3: conv x (w0,1,4,5) + conv C (w6,7) + meta (w3) ----
    if (tid < 128 || (tid >= 256 && tid < 384)) {
      const int c = convC;
      float a0c, a1c, a2c;
      if (convLH == 0) { a0c = ch0; a1c = ch1; a2c = ch2; }
      else {
        a0c = bfu(sRaw[13 * 264 + c]);
        a1c = bfu(sRaw[14 * 264 + c]);
        a2c = bfu(sRaw[15 * 264 + c]);
      }
      unsigned int prev = 0u;
      #pragma unroll
      for (int l = 0; l < 16; ++l) {
        const float a3 = bfu(sRaw[(lt0 + l) * 264 + c]);
        const float acc = cbias + a0c * cw4.x + a1c * cw4.y + a2c * cw4.z + a3 * cw4.w;
        const unsigned int hv = (unsigned int)f2bf(acc * sigmoidf_(acc));
        if (l & 1) *(unsigned int*)(&sXdT[c * 40 + lt0 + l - 1]) = prev | (hv << 16);
        else prev = hv;
        a0c = a1c; a1c = a2c; a2c = a3;
      }
      if (convLH == 0) {
        ch0 = bfu(sRaw[29 * 264 + c]);
        ch1 = bfu(sRaw[30 * 264 + c]);
        ch2 = bfu(sRaw[31 * 264 + c]);
      }
    } else if (tid >= 384) {
      const int c = convC;    // 192..255 -> C col c-192
      float a0c, a1c, a2c;
      if (convLH == 0) { a0c = ch0; a1c = ch1; a2c = ch2; }
      else {
        a0c = bfu(sRaw[13 * 264 + c]);
        a1c = bfu(sRaw[14 * 264 + c]);
        a2c = bfu(sRaw[15 * 264 + c]);
      }
      #pragma unroll
      for (int l = 0; l < 16; ++l) {
        const int lt = lt0 + l;
        const float a3 = bfu(sRaw[lt * 264 + c]);
        const float acc = cbias + a0c * cw4.x + a1c * cw4.y + a2c * cw4.z + a3 * cw4.w;
        sBC16[lt * 136 + 64 + (c - 192)] = f2bf(acc * sigmoidf_(acc));
        a0c = a1c; a1c = a2c; a2c = a3;
      }
      if (convLH == 0) {
        ch0 = bfu(sRaw[29 * 264 + c]);
        ch1 = bfu(sRaw[30 * 264 + c]);
        ch2 = bfu(sRaw[31 * 264 + c]);
      }
    } else if (tid >= 192) {   // wave 3: dt / L meta
      const int ml = tid - 192;
      const int t = ml >> 1, hh = ml & 1;
      const float rawv = sDtRaw[t][hh] + (hh ? dtb1 : dtb0);
      const float dtv = (rawv > 20.f) ? rawv : log1pf(__expf(rawv));
      float Lx = dtv * (hh ? nA1 : nA0);   // log dA_t
      #pragma unroll
      for (int d = 2; d < 64; d <<= 1) {   // inclusive prefix over t
        const float tpv = __shfl_up(Lx, d);
        if (ml >= d) Lx += tpv;
      }
      const float Ltot = __shfl(Lx, 62 + hh);
      *(float4*)(&sMeta[t][hh][0]) =
          make_float4(Lx, dtv, __expf(Ltot - Lx) * dtv, __expf(Lx));
    }
    __syncthreads();   // B3
    // ---- P4: conv B + scaled (w.B)^T (w2,3)  ||  y_inter (w4-7) ----
    f32x4 yAcc[4];
    if (tid >= 128 && tid < 256) {
      const int c = convC, n = c - 128;
      float a0c, a1c, a2c;
      if (convLH == 0) { a0c = ch0; a1c = ch1; a2c = ch2; }
      else {
        a0c = bfu(sRaw[13 * 264 + c]);
        a1c = bfu(sRaw[14 * 264 + c]);
        a2c = bfu(sRaw[15 * 264 + c]);
      }
      unsigned int p0 = 0u, p1 = 0u;
      #pragma unroll
      for (int l = 0; l < 16; ++l) {
        const int lt = lt0 + l;
        const float a3 = bfu(sRaw[lt * 264 + c]);
        const float acc = cbias + a0c * cw4.x + a1c * cw4.y + a2c * cw4.z + a3 * cw4.w;
        const float bv = acc * sigmoidf_(acc);
        sBC16[lt * 136 + n] = f2bf(bv);
        const unsigned int h0 = (unsigned int)f2bf(bv * sMeta[lt][0][2]);
        const unsigned int h1 = (unsigned int)f2bf(bv * sMeta[lt][1][2]);
        if (l & 1) {
          *(unsigned int*)(&sBTw[n * 40 + lt - 1]) = p0 | (h0 << 16);
          *(unsigned int*)(&sBTw[2560 + n * 40 + lt - 1]) = p1 | (h1 << 16);
        } else { p0 = h0; p1 = h1; }
        a0c = a1c; a1c = a2c; a2c = a3;
      }
      if (convLH == 0) {
        ch0 = bfu(sRaw[29 * 264 + c]);
        ch1 = bfu(sRaw[30 * 264 + c]);
        ch2 = bfu(sRaw[31 * 264 + c]);
      }
    } else if (wv >= 4) {
      const int q = wv - 4, th = q >> 1, hq = q & 1;
      if (ck) {
        const bf16x8 ca0 = *(const bf16x8*)(&sBC16[(th * 16 + col) * 136 + 64 + quad * 8]);
        const bf16x8 ca1 = *(const bf16x8*)(&sBC16[(th * 16 + col) * 136 + 96 + quad * 8]);
        #pragma unroll
        for (int pt = 0; pt < 4; ++pt) {
          const unsigned short* hp = &sH[(hq * 64 + pt * 16 + col) * 72];
          const bf16x8 h0 = *(const bf16x8*)(hp + quad * 8);
          const bf16x8 h1 = *(const bf16x8*)(hp + 32 + quad * 8);
          f32x4 d = {0.f, 0.f, 0.f, 0.f};
          d = __builtin_amdgcn_mfma_f32_16x16x32_bf16(ca0, h0, d, 0, 0, 0);
          d = __builtin_amdgcn_mfma_f32_16x16x32_bf16(ca1, h1, d, 0, 0, 0);
          yAcc[pt] = d;
        }
        #pragma unroll
        for (int r = 0; r < 4; ++r) {
          const float Pv = sMeta[th * 16 + quad * 4 + r][hq][3];
          yAcc[0][r] *= Pv; yAcc[1][r] *= Pv; yAcc[2][r] *= Pv; yAcc[3][r] *= Pv;
        }
      } else {
        #pragma unroll
        for (int pt = 0; pt < 4; ++pt) yAcc[pt] = (f32x4){0.f, 0.f, 0.f, 0.f};
      }
    }
    __syncthreads();   // B4
    // ---- P5: h-update (w0-3)  ||  G+mask (w4-6)  ||  zero (0,1) (w7) ----
    if (wv < 4) {
      if (ck < 3) {
        const int h = wv >> 1, pbL = (wv & 1) * 32;
        const float At = sMeta[31][h][3];
        const bf16x8 xa0 = *(const bf16x8*)(&sXdT[(h * 64 + pbL + col) * 40 + quad * 8]);
        const bf16x8 xa1 = *(const bf16x8*)(&sXdT[(h * 64 + pbL + 16 + col) * 40 + quad * 8]);
        #pragma unroll
        for (int nt = 0; nt < 4; ++nt) {
          const bf16x8 bb = *(const bf16x8*)(&sBTw[h * 2560 + (nt * 16 + col) * 40 + quad * 8]);
          #pragma unroll
          for (int r = 0; r < 4; ++r) { hacc[nt][r] *= At; hacc[nt + 4][r] *= At; }
          hacc[nt]     = __builtin_amdgcn_mfma_f32_16x16x32_bf16(xa0, bb, hacc[nt], 0, 0, 0);
          hacc[nt + 4] = __builtin_amdgcn_mfma_f32_16x16x32_bf16(xa1, bb, hacc[nt + 4], 0, 0, 0);
        }
      }
    } else if (wv < 7) {
      const int q = wv - 4;
      const int th = (q > 0) ? 1 : 0, sh = (q == 2) ? 1 : 0;
      const bf16x8 ca0 = *(const bf16x8*)(&sBC16[(th * 16 + col) * 136 + 64 + quad * 8]);
      const bf16x8 ca1 = *(const bf16x8*)(&sBC16[(th * 16 + col) * 136 + 96 + quad * 8]);
      const bf16x8 bb0 = *(const bf16x8*)(&sBC16[(sh * 16 + col) * 136 + quad * 8]);
      const bf16x8 bb1 = *(const bf16x8*)(&sBC16[(sh * 16 + col) * 136 + 32 + quad * 8]);
      f32x4 g = {0.f, 0.f, 0.f, 0.f};
      g = __builtin_amdgcn_mfma_f32_16x16x32_bf16(ca0, bb0, g, 0, 0, 0);
      g = __builtin_amdgcn_mfma_f32_16x16x32_bf16(ca1, bb1, g, 0, 0, 0);
      const int s = sh * 16 + col;
      #pragma unroll
      for (int h = 0; h < 2; ++h) {
        const float Ls = sMeta[s][h][0], dts = sMeta[s][h][1];
        #pragma unroll
        for (int r = 0; r < 4; ++r) {
          const int t = th * 16 + quad * 4 + r;
          const float m = (s <= t) ? __expf(sMeta[t][h][0] - Ls) * dts : 0.f;
          sSm[h * 1280 + t * 40 + s] = f2bf(g[r] * m);
        }
      }
    } else {
      // zero score tile (t<16, s>=16) for both heads (sU clobbered it in P1)
      const int hz = lane >> 5, tz = (lane >> 1) & 15, pz = lane & 1;
      *(uint4*)(&sSm[hz * 1280 + tz * 40 + 16 + pz * 8]) = make_uint4(0u, 0u, 0u, 0u);
    }
    __syncthreads();   // B5
    // ---- P6: y_intra + D*x + y write (w4-7)  ||  h snapshot (w0-3) ----
    if (wv >= 4) {
      const int q = wv - 4, th = q >> 1, hq = q & 1;
      const float dp = hq ? Dp1 : Dp0;
      const bf16x8 sa = *(const bf16x8*)(&sSm[hq * 1280 + (th * 16 + col) * 40 + quad * 8]);
      #pragma unroll
      for (int ct = 0; ct < 4; ++ct) {
        const int c = hq * 64 + ct * 16 + col;
        const bf16x8 xb = *(const bf16x8*)(&sXdT[c * 40 + quad * 8]);
        yAcc[ct] = __builtin_amdgcn_mfma_f32_16x16x32_bf16(sa, xb, yAcc[ct], 0, 0, 0);
        const uint2 xw = *(const uint2*)(&sXdT[c * 40 + th * 16 + quad * 4]);
        yAcc[ct][0] += dp * bflo(xw.x);
        yAcc[ct][1] += dp * bfhi(xw.x);
        yAcc[ct][2] += dp * bflo(xw.y);
        yAcc[ct][3] += dp * bfhi(xw.y);
        #pragma unroll
        for (int r = 0; r < 4; ++r)
          sY[(th * 16 + quad * 4 + r) * 132 + c] = yAcc[ct][r];
      }
    } else if (ck < 3) {
      const int h = wv >> 1, pbL = (wv & 1) * 32;
      #pragma unroll
      for (int nt = 0; nt < 4; ++nt) {
        #pragma unroll
        for (int r = 0; r < 4; ++r) {
          sH[(h * 64 + pbL + quad * 4 + r) * 72 + nt * 16 + col] = f2bf(hacc[nt][r]);
          sH[(h * 64 + pbL + 16 + quad * 4 + r) * 72 + nt * 16 + col] = f2bf(hacc[nt + 4][r]);
        }
      }
    }
    __syncthreads();   // B6
    // ---- P7: gate with silu(z) + rmsnorm -> bf16 g IN PLACE over z ----
    {
      const int k0 = lane << 1;
      #pragma unroll
      for (int sub = 0; sub < 4; ++sub) {
        const int lt = wv + (sub << 3);
        const float2 yv = *(const float2*)(&sY[lt * 132 + k0]);
        const unsigned int zp = *(const unsigned int*)(&sZb[lt * 136 + k0]);
        const float z0 = bflo(zp), z1 = bfhi(zp);
        const float g0 = yv.x * (z0 * sigmoidf_(z0));
        const float g1 = yv.y * (z1 * sigmoidf_(z1));
        float ssq = g0 * g0 + g1 * g1;
        ssq += __shfl_xor(ssq, 1);
        ssq += __shfl_xor(ssq, 2);
        ssq += __shfl_xor(ssq, 4);
        ssq += __shfl_xor(ssq, 8);
        ssq += __shfl_xor(ssq, 16);
        ssq += __shfl_xor(ssq, 32);
        const float sc = rsqrtf(ssq * (1.f / 128.f) + EPSV);
        const float2 nw2 = *(const float2*)(nwA + ip * 128 + k0);
        const unsigned int lo = f2bf(g0 * sc * nw2.x);
        const unsigned int hi = f2bf(g1 * sc * nw2.y);
        *(unsigned int*)(&sZb[lt * 136 + k0]) = lo | (hi << 16);
      }
    }
    __syncthreads();   // B7
    // ---- P8: out-matmul, 8 jobs (row-half, m-tile) over 8 waves ----
    {
      const int rt = wv >> 2, mt = wv & 3;
      const unsigned short* wt = wcf + (mt << 11);
      f32x4 d = {0.f, 0.f, 0.f, 0.f};
      #pragma unroll
      for (int h = 0; h < 4; ++h) {
        const bf16x8 a = *(const bf16x8*)(&sZb[(rt * 16 + col) * 136 + (h << 5) + (quad << 3)]);
        const bf16x8 bb = *(const bf16x8*)(wt + (h << 9) + (lane << 3));
        d = __builtin_amdgcn_mfma_f32_16x16x32_bf16(a, bb, d, 0, 0, 0);
      }
      const size_t yb = ((size_t)(dir * 512 + seq) * 128) << 6;
      #pragma unroll
      for (int r = 0; r < 4; ++r) {
        const int st = (ck << 5) + rt * 16 + (quad << 2) + r;
        const int rp = dir ? (127 - st) : st;
        ybuf[yb + ((size_t)rp << 6) + (mt << 4) + col] = f2bf(d[r]);
      }
    }
    __syncthreads();   // B8
    #pragma unroll
    for (int h = 0; h < 4; ++h) vc[h] = vn[h];
  }
}

// ---------------------------------------------------------------------------
// combine0: x1[b][f][t][c] = x[b][c][t][f] + yf + yb + fb0[c]   (coalesced)
// ---------------------------------------------------------------------------
__global__ __launch_bounds__(256) void combine0(
    const float* __restrict__ x, const unsigned short* __restrict__ ybuf,
    const float* __restrict__ fb, float* __restrict__ x1)
{
  __shared__ float T[64 * 132];
  const int tid = threadIdx.x, blk = blockIdx.x;
  const int b = blk >> 7, t = blk & 127;
  {
    const int c = tid >> 2, f0 = (tid & 3) << 5;
    const float* xp = x + (((size_t)(b * 64 + c) * 128 + t) << 7) + f0;
    float* tp = &T[c * 132 + f0];
    #pragma unroll
    for (int j = 0; j < 8; ++j)
      *(float4*)(tp + (j << 2)) = *(const float4*)(xp + (j << 2));
  }
  __syncthreads();
  {
    const int f = tid >> 1, cb = (tid & 1) << 5;
    const size_t s0 = (size_t)b * 128 + t;
    const unsigned short* yf = ybuf + ((s0 * 128 + f) << 6) + cb;
    const unsigned short* yb = ybuf + (((s0 + 512) * 128 + f) << 6) + cb;
    float* op = x1 + (((size_t)(b * 128 + f) * 128 + t) << 6) + cb;
    #pragma unroll
    for (int j = 0; j < 32; j += 4) {
      float4 v;
      v.x = T[(cb + j + 0) * 132 + f] + bfu(yf[j + 0]) + bfu(yb[j + 0]) + fb[cb + j + 0];
      v.y = T[(cb + j + 1) * 132 + f] + bfu(yf[j + 1]) + bfu(yb[j + 1]) + fb[cb + j + 1];
      v.z = T[(cb + j + 2) * 132 + f] + bfu(yf[j + 2]) + bfu(yb[j + 2]) + fb[cb + j + 2];
      v.w = T[(cb + j + 3) * 132 + f] + bfu(yf[j + 3]) + bfu(yb[j + 3]) + fb[cb + j + 3];
      *(float4*)(op + j) = v;
    }
  }
}

// ---------------------------------------------------------------------------
// combine1: out[b][c][t][f] = x1[b][f][t][c] + yf + yb + fb1[c]  (coalesced)
// ---------------------------------------------------------------------------
__global__ __launch_bounds__(256) void combine1(
    const float* __restrict__ x1, const unsigned short* __restrict__ ybuf,
    const float* __restrict__ fb, float* __restrict__ out)
{
  __shared__ float T[128 * 68];
  const int tid = threadIdx.x, blk = blockIdx.x;
  const int b = blk >> 7, t = blk & 127;
  {
    const int f = tid >> 1, cb = (tid & 1) << 5;
    const size_t s1 = (size_t)b * 128 + f;
    const float* xp = x1 + ((s1 * 128 + t) << 6) + cb;
    const unsigned short* yf = ybuf + ((s1 * 128 + t) << 6) + cb;
    const unsigned short* yb = ybuf + (((s1 + 512) * 128 + t) << 6) + cb;
    float* tp = &T[f * 68 + cb];
    #pragma unroll
    for (int j = 0; j < 32; j += 4) {
      const float4 xv = *(const float4*)(xp + j);
      const uint2 yfv = *(const uint2*)(yf + j);
      const uint2 ybv = *(const uint2*)(yb + j);
      const float4 fv = *(const float4*)(fb + cb + j);
      tp[j + 0] = xv.x + bflo(yfv.x) + bflo(ybv.x) + fv.x;
      tp[j + 1] = xv.y + bfhi(yfv.x) + bfhi(ybv.x) + fv.y;
      tp[j + 2] = xv.z + bflo(yfv.y) + bflo(ybv.y) + fv.z;
      tp[j + 3] = xv.w + bfhi(yfv.y) + bfhi(ybv.y) + fv.w;
    }
  }
  __syncthreads();
  {
    const int c = tid >> 2, f0 = (tid & 3) << 5;
    float* op = out + (((size_t)(b * 64 + c) * 128 + t) << 7) + f0;
    #pragma unroll
    for (int j = 0; j < 32; j += 4) {
      float4 v;
      v.x = T[(f0 + j + 0) * 68 + c];
      v.y = T[(f0 + j + 1) * 68 + c];
      v.z = T[(f0 + j + 2) * 68 + c];
      v.w = T[(f0 + j + 3) * 68 + c];
      *(float4*)(op + j) = v;
    }
  }
}

extern "C" void kernel_launch(void* const* d_in, const int* in_sizes, int n_in,
                              void* d_out, int out_size, void* d_ws, size_t ws_size,
                              hipStream_t stream) {
  const float* x   = (const float*)d_in[0];
  const float* Wp  = (const float*)d_in[1];
  const float* cw  = (const float*)d_in[2];
  const float* cb  = (const float*)d_in[3];
  const float* dtb = (const float*)d_in[4];
  const float* Al  = (const float*)d_in[5];
  const float* Dp  = (const float*)d_in[6];
  const float* nw  = (const float*)d_in[7];
  const float* oW  = (const float*)d_in[8];
  const float* fW  = (const float*)d_in[9];
  const float* fb  = (const float*)d_in[10];
  const float* lnw = (const float*)d_in[11];
  const float* lnb = (const float*)d_in[12];

  float* ws = (float*)d_ws;
  float* Wc = ws;                                       // 32768 f32
  unsigned short* WpF = (unsigned short*)(ws + 32768);  // 102400 shorts
  unsigned short* WcF = (unsigned short*)(ws + 32768 + 51200); // 32768 shorts
  float* xbuf = ws + 32768 + 51200 + 16384;             // 4194304 f32
  unsigned short* y = (unsigned short*)(xbuf + 4194304); // 8388608 bf16

  precomp_wc<<<32, 256, 0, stream>>>(fW, oW, Wc);
  precomp_wcf<<<4, 256, 0, stream>>>(Wc, WcF);
  precomp_wpf<<<4, 256, 0, stream>>>(Wp, WpF);
  transp0<<<512, 256, 0, stream>>>(x, xbuf);
  mamba_dir<<<1024, 512, 0, stream>>>(xbuf, y, WpF, WcF, cw, cb, dtb, Al, Dp,
                                      nw, lnw, lnb, 0);
  combine0<<<512, 256, 0, stream>>>(x, y, fb, xbuf);
  mamba_dir<<<1024, 512, 0, stream>>>(xbuf, y, WpF, WcF, cw, cb, dtb, Al, Dp,
                                      nw, lnw, lnb, 1);
  combine1<<<512, 256, 0, stream>>>(xbuf, y, fb + 64, (float*)d_out);
}